// Round 1
// baseline (106.370 us; speedup 1.0000x reference)
//
#include <hip/hip_runtime.h>

// Problem constants
#define NB   4
#define NC   2
#define NS   4096
#define NKW  64     // K (window)
#define NL   32     // NK (stft rows)
#define NOUT 512

// LDS swizzle: pad every 32 words by 1 -> stride-16 wave access becomes 2-way (free)
__device__ __forceinline__ int sw(int i) { return i + (i >> 5); }

constexpr int XS_PHYS = 4290;  // sw(4159)=4288 max
constexpr int WS_PHYS = 4224;  // sw(4095)=4222 max

// out[b,o,2048r+32m+l] = relu(stft_w[l,m]*H[b,o,r+m] + conv_b[o])
// H[b,o,u] = sum_{c,t} conv_w[o,2048c+t] * xpad[b,c,2t+u],  u in [0,65)
__global__ __launch_bounds__(256, 3)
void fused_cnn(const float* __restrict__ x,
               const float* __restrict__ stft_w,
               const float* __restrict__ conv_w,
               const float* __restrict__ conv_b,
               float* __restrict__ out)
{
    __shared__ float xs[NC * XS_PHYS];  // 34.3 KB
    __shared__ float ws[WS_PHYS];       // 16.9 KB
    __shared__ float Hs[65];

    const int tid = threadIdx.x;
    const int bid = blockIdx.x;
    const int b = bid >> 9;     // / NOUT
    const int o = bid & 511;

    // ---- stage x[b] (both channels), swizzled, zero 63-tail (pad to 64) ----
    for (int c = 0; c < NC; ++c) {
        const float* xb = x + (size_t)(b * NC + c) * NS;
        float* dst = xs + c * XS_PHYS;
        #pragma unroll
        for (int it = 0; it < 4; ++it) {
            int i0 = (it * 256 + tid) * 4;
            float4 v = *(const float4*)(xb + i0);
            dst[sw(i0 + 0)] = v.x;
            dst[sw(i0 + 1)] = v.y;
            dst[sw(i0 + 2)] = v.z;
            dst[sw(i0 + 3)] = v.w;
        }
        if (tid < 64) dst[sw(4096 + tid)] = 0.0f;
    }
    // ---- stage conv_w row, swizzled ----
    {
        const float* wrow = conv_w + (size_t)o * 4096;
        #pragma unroll
        for (int it = 0; it < 4; ++it) {
            int i0 = (it * 256 + tid) * 4;
            float4 v = *(const float4*)(wrow + i0);
            ws[sw(i0 + 0)] = v.x;
            ws[sw(i0 + 1)] = v.y;
            ws[sw(i0 + 2)] = v.z;
            ws[sw(i0 + 3)] = v.w;
        }
    }
    __syncthreads();

    // ---- phase 2: per-wave u-range, lanes split t-groups of 8 ----
    const int wave = tid >> 6;
    const int lane = tid & 63;
    const int u0 = wave << 4;   // 0,16,32,48 ; each wave computes 17 u's

    float acc[17];
    #pragma unroll
    for (int i = 0; i < 17; ++i) acc[i] = 0.0f;

    for (int g = 0; g < 8; ++g) {
        int G = lane + (g << 6);        // 0..511 group id
        int c = G >> 8;
        int t0 = (G & 255) << 3;        // 8 consecutive t per group
        int wb = c * 2048 + t0;
        float w[8];
        #pragma unroll
        for (int j = 0; j < 8; ++j) w[j] = ws[sw(wb + j)];
        const float* xc = xs + c * XS_PHYS;
        int xb0 = 2 * t0 + u0;          // multiple of 16
        #pragma unroll
        for (int d = 0; d <= 30; ++d) { // d = 2j + uu
            float xv = xc[sw(xb0 + d)];
            #pragma unroll
            for (int j = 0; j < 8; ++j) {
                int uu = d - 2 * j;
                if (uu >= 0 && uu < 17)
                    acc[uu] += w[j] * xv;   // 136 FMAs statically kept
            }
        }
    }

    // ---- wave butterfly reduction, lane 0 publishes ----
    #pragma unroll
    for (int uu = 0; uu < 17; ++uu) {
        float v = acc[uu];
        #pragma unroll
        for (int off = 1; off < 64; off <<= 1)
            v += __shfl_xor(v, off, 64);
        acc[uu] = v;
    }
    if (lane == 0) {
        #pragma unroll
        for (int uu = 0; uu < 17; ++uu) {
            if (uu < 16 || wave == 3)   // waves 0-2 own 16 u's, wave 3 owns 17
                Hs[u0 + uu] = acc[uu];
        }
    }
    __syncthreads();

    // ---- epilogue: coalesced float4 stores ----
    const float bias = conv_b[o];
    float* ob = out + (size_t)(b * NOUT + o) * NS;
    #pragma unroll
    for (int it = 0; it < 4; ++it) {
        int s4 = (it * 256 + tid) * 4;  // aligned, l..l+3 within one m
        int r = s4 >> 11;
        int q = s4 & 2047;
        int m = q >> 5;
        int l = q & 31;
        float h = Hs[r + m];
        float v0 = fmaf(stft_w[(l + 0) * NKW + m], h, bias);
        float v1 = fmaf(stft_w[(l + 1) * NKW + m], h, bias);
        float v2 = fmaf(stft_w[(l + 2) * NKW + m], h, bias);
        float v3 = fmaf(stft_w[(l + 3) * NKW + m], h, bias);
        float4 res;
        res.x = v0 > 0.0f ? v0 : 0.0f;
        res.y = v1 > 0.0f ? v1 : 0.0f;
        res.z = v2 > 0.0f ? v2 : 0.0f;
        res.w = v3 > 0.0f ? v3 : 0.0f;
        *(float4*)(ob + s4) = res;
    }
}

extern "C" void kernel_launch(void* const* d_in, const int* in_sizes, int n_in,
                              void* d_out, int out_size, void* d_ws, size_t ws_size,
                              hipStream_t stream) {
    const float* x      = (const float*)d_in[0];
    const float* stft_w = (const float*)d_in[1];
    const float* conv_w = (const float*)d_in[2];
    const float* conv_b = (const float*)d_in[3];
    float* out = (float*)d_out;
    fused_cnn<<<dim3(NB * NOUT), dim3(256), 0, stream>>>(x, stft_w, conv_w, conv_b, out);
}

// Round 2
// 88.434 us; speedup vs baseline: 1.2028x; 1.2028x over previous
//
#include <hip/hip_runtime.h>
#include <hip/hip_bf16.h>

#define NB   4
#define NC   2
#define NS   4096
#define NOUT 512
#define UPAD 80    // stored u-stride in workspace (u<65 consumed)
#define MT   128   // o rows per block in GEMM

typedef short  short8_t  __attribute__((ext_vector_type(8)));
typedef float  float16_t __attribute__((ext_vector_type(16)));

__device__ __forceinline__ short bf16s(float f) {
    union { __hip_bfloat16 b; short s; } u;
    u.b = __float2bfloat16(f);   // RNE via v_cvt
    return u.s;
}

// ---------------------------------------------------------------------------
// Kernel A: split-K GEMM partials.
//   H[b,o,u] = sum_k conv_w[o,k] * Xs[k,u],  Xs[2048c+t, u] = xp[b,c,2t+u]
//   Per block: 128 o-rows x 96 u-cols (u>=80 discarded) x KC k.
//   B-operand trick: xe[i]=xp[2i], xo[i]=xp[2i+1]; Xs[k][u] = (u&1?xo:xe)[k+(u>>1)].
//   8 shifted LDS copies of each parity make every B-fragment (8 consecutive
//   k at fixed u) one 16B-aligned ds_read_b128.
// ---------------------------------------------------------------------------
template<int KCN>
__global__ __launch_bounds__(256)
void gemm_partials(const float* __restrict__ x,
                   const float* __restrict__ conv_w,
                   float* __restrict__ hpart)
{
    constexpr int KC  = 4096 / KCN;   // k per block (<= 2048, single channel)
    constexpr int XSZ = KC + 56;      // staged elems per copy (mult of 8)
    __shared__ __align__(16) short xS[16][XSZ];  // [parity*8 + shift][i]

    const int blk = blockIdx.x;
    const int kc  = blk % KCN;
    const int ot  = (blk / KCN) & 3;          // 4 o-tiles of 128
    const int b   = blk / (KCN * 4);

    const int K0 = kc * KC;
    const int c  = K0 >> 11;                  // channel (KC divides 2048)
    const int tb = K0 & 2047;                 // t offset within channel

    const int tid = threadIdx.x;
    const float* xc = x + (size_t)(b * NC + c) * NS;

    // ---- stage xe/xo with 8 shifted copies, zero-padded past s=4096 ----
    for (int i = tid; i < XSZ; i += 256) {
        int ge = (tb + i) * 2;
        float fe = (ge     < NS) ? xc[ge]     : 0.0f;
        float fo = (ge + 1 < NS) ? xc[ge + 1] : 0.0f;
        short se = bf16s(fe), so = bf16s(fo);
        #pragma unroll
        for (int r = 0; r < 8; ++r) {
            int j = i - r;                    // xS[p*8+r][j] = parity[j+r]
            if (j >= 0) { xS[r][j] = se; xS[8 + r][j] = so; }
        }
    }
    __syncthreads();

    const int wave = tid >> 6;
    const int lane = tid & 63;
    const int l31  = lane & 31;
    const int q    = lane >> 5;               // k-half select
    const int kq   = q * 8;

    const float* wrow = conv_w + (size_t)(ot * MT + wave * 32 + l31) * 4096 + K0;

    float16_t acc[3];
    #pragma unroll
    for (int nt = 0; nt < 3; ++nt)
        #pragma unroll
        for (int e = 0; e < 16; ++e) acc[nt][e] = 0.0f;

    // per-n-tile B addressing (u = 32*nt + l31)
    int arr[3], hb[3];
    #pragma unroll
    for (int nt = 0; nt < 3; ++nt) {
        int uu = nt * 32 + l31;
        int h  = uu >> 1;
        arr[nt] = (uu & 1) * 8 + (h & 7);
        hb[nt]  = h & ~7;
    }

    #pragma unroll 4
    for (int step = 0; step < KC / 16; ++step) {
        const int kl = step * 16 + kq;
        // A fragment: 8 consecutive k of this lane's o-row, fp32->bf16
        float4 a0 = *(const float4*)(wrow + kl);
        float4 a1 = *(const float4*)(wrow + kl + 4);
        short8_t af = { bf16s(a0.x), bf16s(a0.y), bf16s(a0.z), bf16s(a0.w),
                        bf16s(a1.x), bf16s(a1.y), bf16s(a1.z), bf16s(a1.w) };
        #pragma unroll
        for (int nt = 0; nt < 3; ++nt) {
            // one aligned ds_read_b128: Xs[kl+j][u], j=0..7
            short8_t bf = *(const short8_t*)&xS[arr[nt]][kl + hb[nt]];
            acc[nt] = __builtin_amdgcn_mfma_f32_32x32x16_bf16(af, bf, acc[nt], 0, 0, 0);
        }
    }

    // ---- store partials: D layout col=lane&31(u), row=(reg&3)+8*(reg>>2)+4*q
    float* hp = hpart + (size_t)(kc * NB + b) * NOUT * UPAD;
    #pragma unroll
    for (int nt = 0; nt < 3; ++nt) {
        int uu = nt * 32 + l31;
        if (uu < UPAD) {
            #pragma unroll
            for (int reg = 0; reg < 16; ++reg) {
                int row = (reg & 3) + 8 * (reg >> 2) + 4 * q;
                int o   = ot * MT + wave * 32 + row;
                hp[(size_t)o * UPAD + uu] = acc[nt][reg];
            }
        }
    }
}

// ---------------------------------------------------------------------------
// Kernel B: sum split-K partials -> H[65], then validated epilogue:
//   out[b,o,2048r+32m+l] = relu(stft_w[l,m]*H[r+m] + conv_b[o])
// ---------------------------------------------------------------------------
template<int KCN>
__global__ __launch_bounds__(256)
void reduce_epilogue(const float* __restrict__ hpart,
                     const float* __restrict__ stft_w,
                     const float* __restrict__ conv_b,
                     float* __restrict__ out)
{
    __shared__ float Hs[65];
    const int tid = threadIdx.x;
    const int bid = blockIdx.x;
    const int b = bid >> 9;
    const int o = bid & 511;

    if (tid < 65) {
        float h = 0.0f;
        #pragma unroll
        for (int s = 0; s < KCN; ++s)
            h += hpart[((size_t)(s * NB + b) * NOUT + o) * UPAD + tid];
        Hs[tid] = h;
    }
    __syncthreads();

    const float bias = conv_b[o];
    float* ob = out + (size_t)(b * NOUT + o) * NS;
    #pragma unroll
    for (int it = 0; it < 4; ++it) {
        int s4 = (it * 256 + tid) * 4;
        int r  = s4 >> 11;
        int qq = s4 & 2047;
        int m  = qq >> 5;
        int l  = qq & 31;
        float h = Hs[r + m];
        float v0 = fmaf(stft_w[(l + 0) * 64 + m], h, bias);
        float v1 = fmaf(stft_w[(l + 1) * 64 + m], h, bias);
        float v2 = fmaf(stft_w[(l + 2) * 64 + m], h, bias);
        float v3 = fmaf(stft_w[(l + 3) * 64 + m], h, bias);
        float4 res;
        res.x = v0 > 0.0f ? v0 : 0.0f;
        res.y = v1 > 0.0f ? v1 : 0.0f;
        res.z = v2 > 0.0f ? v2 : 0.0f;
        res.w = v3 > 0.0f ? v3 : 0.0f;
        *(float4*)(ob + s4) = res;
    }
}

// ---------------------------------------------------------------------------
template<int KCN>
static void launch_pair(const float* x, const float* stft_w, const float* conv_w,
                        const float* conv_b, float* out, float* ws, hipStream_t stream)
{
    gemm_partials<KCN><<<dim3(NB * 4 * KCN), dim3(256), 0, stream>>>(x, conv_w, ws);
    reduce_epilogue<KCN><<<dim3(NB * NOUT), dim3(256), 0, stream>>>(ws, stft_w, conv_b, out);
}

extern "C" void kernel_launch(void* const* d_in, const int* in_sizes, int n_in,
                              void* d_out, int out_size, void* d_ws, size_t ws_size,
                              hipStream_t stream) {
    const float* x      = (const float*)d_in[0];
    const float* stft_w = (const float*)d_in[1];
    const float* conv_w = (const float*)d_in[2];
    const float* conv_b = (const float*)d_in[3];
    float* out = (float*)d_out;
    float* ws  = (float*)d_ws;

    const size_t per_slice = (size_t)NB * NOUT * UPAD * sizeof(float); // 655360 B
    if      (ws_size >= 16 * per_slice) launch_pair<16>(x, stft_w, conv_w, conv_b, out, ws, stream);
    else if (ws_size >=  8 * per_slice) launch_pair<8>(x, stft_w, conv_w, conv_b, out, ws, stream);
    else if (ws_size >=  4 * per_slice) launch_pair<4 >(x, stft_w, conv_w, conv_b, out, ws, stream);
    else                                launch_pair<2 >(x, stft_w, conv_w, conv_b, out, ws, stream);
}